// Round 3
// baseline (880.804 us; speedup 1.0000x reference)
//
#include <hip/hip_runtime.h>

#define B 2
#define S 2048
#define D 768
#define H 12
#define DH 64
#define TOPK 512
#define NROW (B*S)   // 4096

typedef __attribute__((ext_vector_type(8))) short bf16x8;
typedef __attribute__((ext_vector_type(8))) ushort u16x8;
typedef __attribute__((ext_vector_type(4))) float f32x4;

// ---- bf16 split helpers (hi = RNE bf16 of x, lo = RNE bf16 of residual) ----
__device__ __forceinline__ ushort bf16_hi(float x) {
  union { float f; unsigned u; } v; v.f = x;
  unsigned r = v.u + 0x7fffu + ((v.u >> 16) & 1u);
  return (ushort)(r >> 16);
}
__device__ __forceinline__ float bf16_tof(ushort h) {
  union { float f; unsigned u; } v; v.u = ((unsigned)h) << 16; return v.f;
}
__device__ __forceinline__ void bf16_split(float x, ushort& h, ushort& l) {
  h = bf16_hi(x);
  l = bf16_hi(x - bf16_tof(h));
}
__device__ __forceinline__ float readlane_f(float x, int l) {
  return __uint_as_float(__builtin_amdgcn_readlane(__float_as_uint(x), l));
}

// ---------------------------------------------------------------------------
// Split fp32 tensor -> bf16 hi/lo buffers. 8 elements/thread.
// ---------------------------------------------------------------------------
__global__ __launch_bounds__(256) void split_kernel(
    const float* __restrict__ src, ushort* __restrict__ dh,
    ushort* __restrict__ dl, int n8) {
  int i = blockIdx.x*256 + threadIdx.x;
  if (i >= n8) return;
  float v[8];
  *(float4*)&v[0] = ((const float4*)src)[i*2];
  *(float4*)&v[4] = ((const float4*)src)[i*2+1];
  ushort hh[8], ll[8];
#pragma unroll
  for (int k = 0; k < 8; ++k) bf16_split(v[k], hh[k], ll[k]);
  ((u16x8*)dh)[i] = *(u16x8*)&hh[0];
  ((u16x8*)dl)[i] = *(u16x8*)&ll[0];
}

// ---------------------------------------------------------------------------
// Split-bf16 MFMA GEMM: C = A (N x 768) @ W^T + bias, * scale
// A given as Ah/Al bf16 split, W as Wh/Wl. 4-term product => ~fp32 exact.
// Block 256 = 4 waves, tile 64x64, wave tile 32x32 (2x2 fragments).
// MODE 0: C row-major [N][768] fp32 (final output)
// MODE 1: C scattered to [b][h][s][dh] fp32 (QKV projections)
// ---------------------------------------------------------------------------
template<int MODE>
__global__ __launch_bounds__(256) void projmf_kernel(
    const ushort* __restrict__ Ah, const ushort* __restrict__ Al,
    const ushort* __restrict__ Wh, const ushort* __restrict__ Wl,
    const float* __restrict__ bias, float* __restrict__ C, float scale) {
  int tid = threadIdx.x;
  int w = tid >> 6, lane = tid & 63;
  int lr = lane & 15, lg = lane >> 4;
  int n0 = blockIdx.x*64 + (w >> 1)*32;
  int m0 = blockIdx.y*64 + (w & 1)*32;
  f32x4 acc[2][2] = {};
  for (int ks = 0; ks < 24; ++ks) {
    int ko = ks*32 + lg*8;
    bf16x8 ah[2], al[2], wh[2], wl[2];
#pragma unroll
    for (int i = 0; i < 2; ++i) {
      size_t ao = (size_t)(n0 + 16*i + lr)*768 + ko;
      ah[i] = *(const bf16x8*)(Ah + ao);
      al[i] = *(const bf16x8*)(Al + ao);
      size_t wo = (size_t)(m0 + 16*i + lr)*768 + ko;
      wh[i] = *(const bf16x8*)(Wh + wo);
      wl[i] = *(const bf16x8*)(Wl + wo);
    }
#pragma unroll
    for (int i = 0; i < 2; ++i)
#pragma unroll
      for (int j = 0; j < 2; ++j) {
        acc[i][j] = __builtin_amdgcn_mfma_f32_16x16x32_bf16(ah[i], wh[j], acc[i][j], 0, 0, 0);
        acc[i][j] = __builtin_amdgcn_mfma_f32_16x16x32_bf16(ah[i], wl[j], acc[i][j], 0, 0, 0);
        acc[i][j] = __builtin_amdgcn_mfma_f32_16x16x32_bf16(al[i], wh[j], acc[i][j], 0, 0, 0);
        acc[i][j] = __builtin_amdgcn_mfma_f32_16x16x32_bf16(al[i], wl[j], acc[i][j], 0, 0, 0);
      }
  }
#pragma unroll
  for (int i = 0; i < 2; ++i)
#pragma unroll
    for (int j = 0; j < 2; ++j) {
      int m = m0 + 16*j + lr;
      float bv = bias[m];
#pragma unroll
      for (int r = 0; r < 4; ++r) {
        int n = n0 + 16*i + lg*4 + r;
        float val = (acc[i][j][r] + bv) * scale;
        if (MODE == 0) {
          C[(size_t)n*D + m] = val;
        } else {
          int b = n >> 11, s = n & 2047, hh = m >> 6, dh = m & 63;
          C[(((size_t)b*H + hh)*S + s)*DH + dh] = val;
        }
      }
    }
}

// ---------------------------------------------------------------------------
// Leverage stage A1: per-head partial KtK over 128-row chunks (batch 0 only)
// ---------------------------------------------------------------------------
__global__ __launch_bounds__(256) void levA1_kernel(
    const float* __restrict__ Kmat, float* __restrict__ partials) {
  int h = blockIdx.x, blk = blockIdx.y;
  __shared__ __align__(16) float ktile[128*64];
  int tid = threadIdx.x;
  const float* Kh = Kmat + ((size_t)h*S + (size_t)blk*128)*DH;
#pragma unroll
  for (int r = 0; r < 32; ++r) { int e = tid + 256*r; ktile[e] = Kh[e]; }
  __syncthreads();
  int j4 = tid & 15;
  float accf[4][4] = {};
  for (int ss = 0; ss < 128; ++ss) {
    float4 kj = ((const float4*)(ktile + ss*64))[j4];
#pragma unroll
    for (int r = 0; r < 4; ++r) {
      int i = (tid >> 4) + 16*r;
      float ki = ktile[ss*64 + i];
      accf[r][0] += ki*kj.x; accf[r][1] += ki*kj.y;
      accf[r][2] += ki*kj.z; accf[r][3] += ki*kj.w;
    }
  }
  size_t base = ((size_t)h*16 + blk)*4096;
#pragma unroll
  for (int r = 0; r < 4; ++r) {
    int i = (tid >> 4) + 16*r;
#pragma unroll
    for (int c = 0; c < 4; ++c)
      partials[base + (size_t)i*64 + j4*4 + c] = accf[r][c];
  }
}

// ---------------------------------------------------------------------------
// Leverage stage A2: one WAVE per head. fp64 reduce (same order as before),
// then in-place Gauss-Jordan in registers: lane j holds column j.
// Zero barriers, zero LDS. Arithmetic sequence identical to the LDS version.
// ---------------------------------------------------------------------------
__global__ __launch_bounds__(64) void levA2_kernel(
    const float* __restrict__ partials, float* __restrict__ invOut) {
  int h = blockIdx.x, j = threadIdx.x;
  float a[64];
  const float* pb = partials + (size_t)h*16*4096 + j;
#pragma unroll
  for (int i = 0; i < 64; ++i) {
    double t = 0.0;
#pragma unroll
    for (int p = 0; p < 16; ++p) t += (double)pb[(size_t)p*4096 + i*64];
    if (i == j) t += 1e-6;
    a[i] = (float)t;
  }
#pragma unroll
  for (int p = 0; p < 64; ++p) {
    float piv = readlane_f(a[p], p);
    float ipiv = 1.0f / piv;
    a[p] = (j == p) ? ipiv : a[p] * ipiv;
#pragma unroll
    for (int i = 0; i < 64; ++i) {
      if (i == p) continue;
      float f = readlane_f(a[i], p);
      float base = (j == p) ? 0.0f : a[i];
      a[i] = fmaf(-f, a[p], base);
    }
  }
#pragma unroll
  for (int i = 0; i < 64; ++i)
    invOut[(size_t)h*4096 + i*64 + j] = a[i];
}

// ---------------------------------------------------------------------------
// Leverage stage B: lev[h][s] = k_s^T inv_h k_s
// ---------------------------------------------------------------------------
__global__ __launch_bounds__(256) void levB_kernel(
    const float* __restrict__ Kmat, const float* __restrict__ invMat,
    float* __restrict__ lev) {
  int h = blockIdx.x;
  int s = blockIdx.y*256 + threadIdx.x;
  __shared__ __align__(16) float inv[64*64];
#pragma unroll
  for (int r = 0; r < 16; ++r)
    inv[threadIdx.x + 256*r] = invMat[(size_t)h*4096 + threadIdx.x + 256*r];
  __syncthreads();
  float kv[64];
  const float* kr = Kmat + ((size_t)h*S + s)*DH;
#pragma unroll
  for (int d4 = 0; d4 < 16; ++d4) {
    float4 t = ((const float4*)kr)[d4];
    kv[4*d4+0]=t.x; kv[4*d4+1]=t.y; kv[4*d4+2]=t.z; kv[4*d4+3]=t.w;
  }
  float acc = 0.f;
  for (int i = 0; i < 64; ++i) {
    float ti = 0.f;
    const float4* ir = (const float4*)(inv + i*64);
#pragma unroll
    for (int j4 = 0; j4 < 16; ++j4) {
      float4 iv = ir[j4];
      ti += iv.x*kv[4*j4] + iv.y*kv[4*j4+1] + iv.z*kv[4*j4+2] + iv.w*kv[4*j4+3];
    }
    acc += ti * kv[i];
  }
  lev[(size_t)h*S + s] = acc;
}

// ---------------------------------------------------------------------------
// Top-k via bitonic sort (value desc, index asc)
// ---------------------------------------------------------------------------
__global__ __launch_bounds__(256) void topk_kernel(
    const float* __restrict__ lev, int* __restrict__ idx_list) {
  int h = blockIdx.x, tid = threadIdx.x;
  __shared__ float sv[2048];
  __shared__ int   si[2048];
#pragma unroll
  for (int r = 0; r < 8; ++r) {
    int e = tid + 256*r;
    sv[e] = lev[(size_t)h*S + e];
    si[e] = e;
  }
  __syncthreads();
  for (int k = 2; k <= 2048; k <<= 1) {
    for (int j = k >> 1; j > 0; j >>= 1) {
      for (int r = 0; r < 8; ++r) {
        int i = tid + 256*r;
        int l = i ^ j;
        if (l > i) {
          float v1 = sv[i], v2 = sv[l];
          int   i1 = si[i], i2 = si[l];
          bool before = (v1 > v2) || (v1 == v2 && i1 < i2);
          bool dir = ((i & k) == 0);
          if (before != dir) { sv[i]=v2; sv[l]=v1; si[i]=i2; si[l]=i1; }
        }
      }
      __syncthreads();
    }
  }
#pragma unroll
  for (int r = 0; r < 2; ++r) {
    int t = tid + 256*r;
    idx_list[h*TOPK + t] = si[t];
  }
}

// ---------------------------------------------------------------------------
// Gather kept K/V rows -> bf16 split buffers.
// KCh/KCl: [bh][512][64]; VCth/VCtl: [bh][64][512] (transposed)
// ---------------------------------------------------------------------------
__global__ __launch_bounds__(256) void gather_kernel(
    const float* __restrict__ Kmat, const float* __restrict__ Vmat,
    const int* __restrict__ idx_list,
    ushort* __restrict__ KCh, ushort* __restrict__ KCl,
    ushort* __restrict__ VCth, ushort* __restrict__ VCtl) {
  int bh = blockIdx.x;        // 0..23
  int kc = blockIdx.y;        // 0..7
  int h = bh % H;
  __shared__ float vt[64][65];
  int tid = threadIdx.x;
  int kk = tid >> 2;           // key within chunk (0..63)
  int dq = (tid & 3) * 16;     // dh base (0,16,32,48)
  int j = kc*64 + kk;
  int srow = idx_list[h*TOPK + j];
  const float* kr = Kmat + ((size_t)bh*S + srow)*DH + dq;
  const float* vr = Vmat + ((size_t)bh*S + srow)*DH + dq;
  ushort hh[16], ll[16];
#pragma unroll
  for (int i = 0; i < 16; ++i) bf16_split(kr[i], hh[i], ll[i]);
  size_t kbase = ((size_t)bh*TOPK + j)*DH + dq;
  *(u16x8*)(KCh + kbase)     = *(u16x8*)&hh[0];
  *(u16x8*)(KCh + kbase + 8) = *(u16x8*)&hh[8];
  *(u16x8*)(KCl + kbase)     = *(u16x8*)&ll[0];
  *(u16x8*)(KCl + kbase + 8) = *(u16x8*)&ll[8];
#pragma unroll
  for (int i = 0; i < 16; ++i) vt[kk][dq + i] = vr[i];
  __syncthreads();
  int d  = tid >> 2;           // dh row (0..63)
  int kq = (tid & 3) * 16;     // key base within chunk
#pragma unroll
  for (int i = 0; i < 16; ++i) bf16_split(vt[kq + i][d], hh[i], ll[i]);
  size_t vbase = ((size_t)bh*DH + d)*TOPK + kc*64 + kq;
  *(u16x8*)(VCth + vbase)     = *(u16x8*)&hh[0];
  *(u16x8*)(VCth + vbase + 8) = *(u16x8*)&hh[8];
  *(u16x8*)(VCtl + vbase)     = *(u16x8*)&ll[0];
  *(u16x8*)(VCtl + vbase + 8) = *(u16x8*)&ll[8];
}

// ---------------------------------------------------------------------------
// MFMA attention, split-bf16: single pass, 4 waves/block, wave-private LDS.
// Epilogue writes CTX as bf16 hi/lo (feeds the MFMA output projection).
// ---------------------------------------------------------------------------
__global__ __launch_bounds__(256) void attn_kernel(
    const float* __restrict__ Q,
    const ushort* __restrict__ KCh, const ushort* __restrict__ KCl,
    const ushort* __restrict__ VCth, const ushort* __restrict__ VCtl,
    ushort* __restrict__ CTXh, ushort* __restrict__ CTXl) {
  __shared__ __align__(16) ushort SQh[4][16][88];
  __shared__ __align__(16) ushort SQl[4][16][88];
  int tid = threadIdx.x;
  int w = tid >> 6;
  int lane = tid & 63;
  int lr = lane & 15, lg = lane >> 4;
  int bh = blockIdx.x >> 5;
  int qt = blockIdx.x & 31;
  int qbase = qt*64 + w*16;
  int b = bh / H, h = bh % H;

  bf16x8 qh[2], ql[2];
#pragma unroll
  for (int ks = 0; ks < 2; ++ks) {
    const float* qp = Q + ((size_t)bh*S + qbase + lr)*DH + ks*32 + lg*8;
    float qv[8];
    *(float4*)&qv[0] = *(const float4*)qp;
    *(float4*)&qv[4] = *(const float4*)(qp + 4);
#pragma unroll
    for (int i = 0; i < 8; ++i) {
      ushort hh, lo; bf16_split(qv[i], hh, lo);
      qh[ks][i] = (short)hh; ql[ks][i] = (short)lo;
    }
  }

  f32x4 pacc[4] = {};
  float z_acc[4] = {};

  for (int c = 0; c < 8; ++c) {
    int keybase = c*64;
    f32x4 sacc[4] = {};
#pragma unroll
    for (int ks = 0; ks < 2; ++ks) {
#pragma unroll
      for (int f = 0; f < 4; ++f) {
        size_t koff = ((size_t)bh*TOPK + keybase + 16*f + lr)*DH + ks*32 + lg*8;
        bf16x8 kh = *(const bf16x8*)(KCh + koff);
        bf16x8 kl = *(const bf16x8*)(KCl + koff);
        sacc[f] = __builtin_amdgcn_mfma_f32_16x16x32_bf16(qh[ks], kh, sacc[f], 0, 0, 0);
        sacc[f] = __builtin_amdgcn_mfma_f32_16x16x32_bf16(qh[ks], kl, sacc[f], 0, 0, 0);
        sacc[f] = __builtin_amdgcn_mfma_f32_16x16x32_bf16(ql[ks], kh, sacc[f], 0, 0, 0);
      }
    }
    float zc[4] = {};
#pragma unroll
    for (int f = 0; f < 4; ++f) {
#pragma unroll
      for (int r = 0; r < 4; ++r) {
        float s = sacc[f][r];
        float sq = s*s;
        zc[r] += sq;
        ushort hh, lo; bf16_split(sq, hh, lo);
        SQh[w][lg*4 + r][16*f + lr] = hh;
        SQl[w][lg*4 + r][16*f + lr] = lo;
      }
    }
#pragma unroll
    for (int r = 0; r < 4; ++r) {
      float t = zc[r];
      t += __shfl_xor(t, 1);
      t += __shfl_xor(t, 2);
      t += __shfl_xor(t, 4);
      t += __shfl_xor(t, 8);
      z_acc[r] += t;
    }
#pragma unroll
    for (int ks = 0; ks < 2; ++ks) {
      bf16x8 ah = *(const bf16x8*)&SQh[w][lr][ks*32 + lg*8];
      bf16x8 al = *(const bf16x8*)&SQl[w][lr][ks*32 + lg*8];
#pragma unroll
      for (int f = 0; f < 4; ++f) {
        size_t voff = ((size_t)bh*DH + 16*f + lr)*TOPK + keybase + ks*32 + lg*8;
        bf16x8 vh = *(const bf16x8*)(VCth + voff);
        bf16x8 vl = *(const bf16x8*)(VCtl + voff);
        pacc[f] = __builtin_amdgcn_mfma_f32_16x16x32_bf16(ah, vh, pacc[f], 0, 0, 0);
        pacc[f] = __builtin_amdgcn_mfma_f32_16x16x32_bf16(ah, vl, pacc[f], 0, 0, 0);
        pacc[f] = __builtin_amdgcn_mfma_f32_16x16x32_bf16(al, vh, pacc[f], 0, 0, 0);
      }
    }
  }

  float zi[4];
#pragma unroll
  for (int r = 0; r < 4; ++r) zi[r] = 1.0f / (z_acc[r] + 1e-12f);
#pragma unroll
  for (int f = 0; f < 4; ++f) {
#pragma unroll
    for (int r = 0; r < 4; ++r) {
      int q = lg*4 + r;
      float val = pacc[f][r] * zi[r];
      ushort hh, lo; bf16_split(val, hh, lo);
      size_t o = ((size_t)b*S + qbase + q)*D + h*DH + 16*f + lr;
      CTXh[o] = hh; CTXl[o] = lo;
    }
  }
}

// ---------------------------------------------------------------------------
extern "C" void kernel_launch(void* const* d_in, const int* in_sizes, int n_in,
                              void* d_out, int out_size, void* d_ws, size_t ws_size,
                              hipStream_t stream) {
  const float* query = (const float*)d_in[0];
  const float* key   = (const float*)d_in[1];
  const float* value = (const float*)d_in[2];
  const float* Wq = (const float*)d_in[3];
  const float* bq = (const float*)d_in[4];
  const float* Wk = (const float*)d_in[5];
  const float* bk = (const float*)d_in[6];
  const float* Wv = (const float*)d_in[7];
  const float* bv = (const float*)d_in[8];
  const float* Wo = (const float*)d_in[9];
  const float* bo = (const float*)d_in[10];
  float* out = (float*)d_out;

  float* ws = (float*)d_ws;
  const size_t QKV = (size_t)B*H*S*DH;        // 3,145,728
  const size_t WSZ = (size_t)D*D;             // 589,824
  float* Qws   = ws;
  float* Kws   = Qws + QKV;
  float* Vws   = Kws + QKV;
  float* partials = Vws + QKV;                // 786,432
  float* invWs = partials + (size_t)H*16*4096;
  float* levWs = invWs + (size_t)H*4096;
  ushort* Xh  = (ushort*)(levWs + (size_t)H*S);   // input split / later CTX
  ushort* Xl  = Xh + QKV;
  ushort* Wqh = Xl + QKV;  ushort* Wql = Wqh + WSZ;
  ushort* Wkh = Wql + WSZ; ushort* Wkl = Wkh + WSZ;
  ushort* Wvh = Wkl + WSZ; ushort* Wvl = Wvh + WSZ;
  ushort* Woh = Wvl + WSZ; ushort* Wol = Woh + WSZ;
  ushort* KCh  = Wol + WSZ;
  ushort* KCl  = KCh  + (size_t)B*H*TOPK*DH;
  ushort* VCth = KCl  + (size_t)B*H*TOPK*DH;
  ushort* VCtl = VCth + (size_t)B*H*TOPK*DH;
  int*   idxWs = (int*)(VCtl + (size_t)B*H*TOPK*DH);

  const int nW8 = (int)(WSZ/8), nX8 = (int)(QKV/8);
  split_kernel<<<nW8/256, 256, 0, stream>>>(Wq, Wqh, Wql, nW8);
  split_kernel<<<nW8/256, 256, 0, stream>>>(Wk, Wkh, Wkl, nW8);
  split_kernel<<<nW8/256, 256, 0, stream>>>(Wv, Wvh, Wvl, nW8);
  split_kernel<<<nW8/256, 256, 0, stream>>>(Wo, Woh, Wol, nW8);

  dim3 pgrid(NROW/64, D/64);
  split_kernel<<<nX8/256, 256, 0, stream>>>(query, Xh, Xl, nX8);
  projmf_kernel<1><<<pgrid, 256, 0, stream>>>(Xh, Xl, Wqh, Wql, bq, Qws, 0.125f);
  split_kernel<<<nX8/256, 256, 0, stream>>>(key, Xh, Xl, nX8);
  projmf_kernel<1><<<pgrid, 256, 0, stream>>>(Xh, Xl, Wkh, Wkl, bk, Kws, 1.0f);
  split_kernel<<<nX8/256, 256, 0, stream>>>(value, Xh, Xl, nX8);
  projmf_kernel<1><<<pgrid, 256, 0, stream>>>(Xh, Xl, Wvh, Wvl, bv, Vws, 1.0f);

  levA1_kernel<<<dim3(H,16), 256, 0, stream>>>(Kws, partials);
  levA2_kernel<<<H, 64, 0, stream>>>(partials, invWs);
  levB_kernel<<<dim3(H,8), 256, 0, stream>>>(Kws, invWs, levWs);
  topk_kernel<<<H, 256, 0, stream>>>(levWs, idxWs);

  gather_kernel<<<dim3(B*H, TOPK/64), 256, 0, stream>>>(
      Kws, Vws, idxWs, KCh, KCl, VCth, VCtl);

  // attn writes CTX split into Xh/Xl (input splits are dead by now)
  attn_kernel<<<B*H*(S/64), 256, 0, stream>>>(Qws, KCh, KCl, VCth, VCtl, Xh, Xl);

  projmf_kernel<0><<<pgrid, 256, 0, stream>>>(Xh, Xl, Woh, Wol, bo, out, 1.0f);
}

// Round 4
// 832.984 us; speedup vs baseline: 1.0574x; 1.0574x over previous
//
#include <hip/hip_runtime.h>

#define B 2
#define S 2048
#define D 768
#define H 12
#define DH 64
#define TOPK 512
#define NROW (B*S)   // 4096

typedef __attribute__((ext_vector_type(8))) short bf16x8;
typedef __attribute__((ext_vector_type(8))) ushort u16x8;
typedef __attribute__((ext_vector_type(4))) float f32x4;

// ---- bf16 split helpers (hi = RNE bf16 of x, lo = RNE bf16 of residual) ----
__device__ __forceinline__ ushort bf16_hi(float x) {
  union { float f; unsigned u; } v; v.f = x;
  unsigned r = v.u + 0x7fffu + ((v.u >> 16) & 1u);
  return (ushort)(r >> 16);
}
__device__ __forceinline__ float bf16_tof(ushort h) {
  union { float f; unsigned u; } v; v.u = ((unsigned)h) << 16; return v.f;
}
__device__ __forceinline__ void bf16_split(float x, ushort& h, ushort& l) {
  h = bf16_hi(x);
  l = bf16_hi(x - bf16_tof(h));
}
__device__ __forceinline__ float readlane_f(float x, int l) {
  return __uint_as_float(__builtin_amdgcn_readlane(__float_as_uint(x), l));
}

// ---------------------------------------------------------------------------
// Split fp32 tensor -> bf16 hi/lo buffers. 8 elements/thread.
// ---------------------------------------------------------------------------
__global__ __launch_bounds__(256) void split_kernel(
    const float* __restrict__ src, ushort* __restrict__ dh,
    ushort* __restrict__ dl, int n8) {
  int i = blockIdx.x*256 + threadIdx.x;
  if (i >= n8) return;
  float v[8];
  *(float4*)&v[0] = ((const float4*)src)[i*2];
  *(float4*)&v[4] = ((const float4*)src)[i*2+1];
  ushort hh[8], ll[8];
#pragma unroll
  for (int k = 0; k < 8; ++k) bf16_split(v[k], hh[k], ll[k]);
  ((u16x8*)dh)[i] = *(u16x8*)&hh[0];
  ((u16x8*)dl)[i] = *(u16x8*)&ll[0];
}

// ---------------------------------------------------------------------------
// Split-bf16 MFMA GEMM: C = A (N x 768) @ W^T + bias, * scale
// Block 256 = 4 waves, tile 64x64, wave tile 32x32 (2x2 fragments).
// MODE 0: C row-major [N][768] fp32; MODE 1: C scattered to [b][h][s][dh]
// ---------------------------------------------------------------------------
template<int MODE>
__global__ __launch_bounds__(256) void projmf_kernel(
    const ushort* __restrict__ Ah, const ushort* __restrict__ Al,
    const ushort* __restrict__ Wh, const ushort* __restrict__ Wl,
    const float* __restrict__ bias, float* __restrict__ C, float scale) {
  int tid = threadIdx.x;
  int w = tid >> 6, lane = tid & 63;
  int lr = lane & 15, lg = lane >> 4;
  int n0 = blockIdx.x*64 + (w >> 1)*32;
  int m0 = blockIdx.y*64 + (w & 1)*32;
  f32x4 acc[2][2] = {};
  for (int ks = 0; ks < 24; ++ks) {
    int ko = ks*32 + lg*8;
    bf16x8 ah[2], al[2], wh[2], wl[2];
#pragma unroll
    for (int i = 0; i < 2; ++i) {
      size_t ao = (size_t)(n0 + 16*i + lr)*768 + ko;
      ah[i] = *(const bf16x8*)(Ah + ao);
      al[i] = *(const bf16x8*)(Al + ao);
      size_t wo = (size_t)(m0 + 16*i + lr)*768 + ko;
      wh[i] = *(const bf16x8*)(Wh + wo);
      wl[i] = *(const bf16x8*)(Wl + wo);
    }
#pragma unroll
    for (int i = 0; i < 2; ++i)
#pragma unroll
      for (int j = 0; j < 2; ++j) {
        acc[i][j] = __builtin_amdgcn_mfma_f32_16x16x32_bf16(ah[i], wh[j], acc[i][j], 0, 0, 0);
        acc[i][j] = __builtin_amdgcn_mfma_f32_16x16x32_bf16(ah[i], wl[j], acc[i][j], 0, 0, 0);
        acc[i][j] = __builtin_amdgcn_mfma_f32_16x16x32_bf16(al[i], wh[j], acc[i][j], 0, 0, 0);
        acc[i][j] = __builtin_amdgcn_mfma_f32_16x16x32_bf16(al[i], wl[j], acc[i][j], 0, 0, 0);
      }
  }
#pragma unroll
  for (int i = 0; i < 2; ++i)
#pragma unroll
    for (int j = 0; j < 2; ++j) {
      int m = m0 + 16*j + lr;
      float bv = bias[m];
#pragma unroll
      for (int r = 0; r < 4; ++r) {
        int n = n0 + 16*i + lg*4 + r;
        float val = (acc[i][j][r] + bv) * scale;
        if (MODE == 0) {
          C[(size_t)n*D + m] = val;
        } else {
          int b = n >> 11, s = n & 2047, hh = m >> 6, dh = m & 63;
          C[(((size_t)b*H + hh)*S + s)*DH + dh] = val;
        }
      }
    }
}

// ---------------------------------------------------------------------------
// Leverage stage A1: per-head partial KtK over 128-row chunks (batch 0 only)
// ---------------------------------------------------------------------------
__global__ __launch_bounds__(256) void levA1_kernel(
    const float* __restrict__ Kmat, float* __restrict__ partials) {
  int h = blockIdx.x, blk = blockIdx.y;
  __shared__ __align__(16) float ktile[128*64];
  int tid = threadIdx.x;
  const float* Kh = Kmat + ((size_t)h*S + (size_t)blk*128)*DH;
#pragma unroll
  for (int r = 0; r < 32; ++r) { int e = tid + 256*r; ktile[e] = Kh[e]; }
  __syncthreads();
  int j4 = tid & 15;
  float accf[4][4] = {};
  for (int ss = 0; ss < 128; ++ss) {
    float4 kj = ((const float4*)(ktile + ss*64))[j4];
#pragma unroll
    for (int r = 0; r < 4; ++r) {
      int i = (tid >> 4) + 16*r;
      float ki = ktile[ss*64 + i];
      accf[r][0] += ki*kj.x; accf[r][1] += ki*kj.y;
      accf[r][2] += ki*kj.z; accf[r][3] += ki*kj.w;
    }
  }
  size_t base = ((size_t)h*16 + blk)*4096;
#pragma unroll
  for (int r = 0; r < 4; ++r) {
    int i = (tid >> 4) + 16*r;
#pragma unroll
    for (int c = 0; c < 4; ++c)
      partials[base + (size_t)i*64 + j4*4 + c] = accf[r][c];
  }
}

// ---------------------------------------------------------------------------
// Leverage stage A2: ONE WAVE per head, augmented [A|I] Gauss-Jordan in LDS,
// row-ownership (lane j owns row j). Arithmetic sequence identical to the
// R2 256-thread version (fcol read before normalize; n = rp*ipiv; fma
// update), but barrier-free pivot body and no register arrays (no spill).
// LDS stride 130 floats: 2-way bank aliasing (free), rows 8B-aligned.
// ---------------------------------------------------------------------------
__global__ __launch_bounds__(64) void levA2_kernel(
    const float* __restrict__ partials, float* __restrict__ invOut) {
  int h = blockIdx.x, j = threadIdx.x;
  __shared__ float A_[64][130];
  const float* pb = partials + (size_t)h*65536;
  for (int i = 0; i < 64; ++i) {
    double t = 0.0;
#pragma unroll
    for (int p = 0; p < 16; ++p) t += (double)pb[(size_t)p*4096 + (size_t)i*64 + j];
    if (i == j) t += 1e-6;
    A_[i][j] = (float)t;
    A_[i][64 + j] = (i == j) ? 1.0f : 0.0f;
  }
  __syncthreads();
  for (int p = 0; p < 64; ++p) {
    float f = A_[j][p];                 // fcol[j], read BEFORE normalize
    float piv = readlane_f(f, p);       // A[p][p]
    float ipiv = 1.0f / piv;
    bool isp = (j == p);
#pragma unroll 8
    for (int c2 = 0; c2 < 64; ++c2) {
      float2 rp = *(const float2*)&A_[p][c2*2];   // broadcast (old row p)
      float2 rj = *(const float2*)&A_[j][c2*2];   // own row
      float n0 = rp.x * ipiv, n1 = rp.y * ipiv;   // normalized row p
      float o0 = isp ? n0 : fmaf(-f, n0, rj.x);
      float o1 = isp ? n1 : fmaf(-f, n1, rj.y);
      *(float2*)&A_[j][c2*2] = make_float2(o0, o1);
    }
    __syncthreads();                    // single-wave: just a waitcnt
  }
  for (int i = 0; i < 64; ++i)
    invOut[(size_t)h*4096 + (size_t)i*64 + j] = A_[i][64 + j];
}

// ---------------------------------------------------------------------------
// Leverage stage B: lev[h][s] = k_s^T inv_h k_s
// ---------------------------------------------------------------------------
__global__ __launch_bounds__(256) void levB_kernel(
    const float* __restrict__ Kmat, const float* __restrict__ invMat,
    float* __restrict__ lev) {
  int h = blockIdx.x;
  int s = blockIdx.y*256 + threadIdx.x;
  __shared__ __align__(16) float inv[64*64];
#pragma unroll
  for (int r = 0; r < 16; ++r)
    inv[threadIdx.x + 256*r] = invMat[(size_t)h*4096 + threadIdx.x + 256*r];
  __syncthreads();
  float kv[64];
  const float* kr = Kmat + ((size_t)h*S + s)*DH;
#pragma unroll
  for (int d4 = 0; d4 < 16; ++d4) {
    float4 t = ((const float4*)kr)[d4];
    kv[4*d4+0]=t.x; kv[4*d4+1]=t.y; kv[4*d4+2]=t.z; kv[4*d4+3]=t.w;
  }
  float acc = 0.f;
  for (int i = 0; i < 64; ++i) {
    float ti = 0.f;
    const float4* ir = (const float4*)(inv + i*64);
#pragma unroll
    for (int j4 = 0; j4 < 16; ++j4) {
      float4 iv = ir[j4];
      ti += iv.x*kv[4*j4] + iv.y*kv[4*j4+1] + iv.z*kv[4*j4+2] + iv.w*kv[4*j4+3];
    }
    acc += ti * kv[i];
  }
  lev[(size_t)h*S + s] = acc;
}

// ---------------------------------------------------------------------------
// Top-k via bitonic sort (value desc, index asc)
// ---------------------------------------------------------------------------
__global__ __launch_bounds__(256) void topk_kernel(
    const float* __restrict__ lev, int* __restrict__ idx_list) {
  int h = blockIdx.x, tid = threadIdx.x;
  __shared__ float sv[2048];
  __shared__ int   si[2048];
#pragma unroll
  for (int r = 0; r < 8; ++r) {
    int e = tid + 256*r;
    sv[e] = lev[(size_t)h*S + e];
    si[e] = e;
  }
  __syncthreads();
  for (int k = 2; k <= 2048; k <<= 1) {
    for (int j = k >> 1; j > 0; j >>= 1) {
      for (int r = 0; r < 8; ++r) {
        int i = tid + 256*r;
        int l = i ^ j;
        if (l > i) {
          float v1 = sv[i], v2 = sv[l];
          int   i1 = si[i], i2 = si[l];
          bool before = (v1 > v2) || (v1 == v2 && i1 < i2);
          bool dir = ((i & k) == 0);
          if (before != dir) { sv[i]=v2; sv[l]=v1; si[i]=i2; si[l]=i1; }
        }
      }
      __syncthreads();
    }
  }
#pragma unroll
  for (int r = 0; r < 2; ++r) {
    int t = tid + 256*r;
    idx_list[h*TOPK + t] = si[t];
  }
}

// ---------------------------------------------------------------------------
// Gather kept K/V rows -> bf16 split buffers.
// KCh/KCl: [bh][512][64]; VCth/VCtl: [bh][64][512] (transposed)
// ---------------------------------------------------------------------------
__global__ __launch_bounds__(256) void gather_kernel(
    const float* __restrict__ Kmat, const float* __restrict__ Vmat,
    const int* __restrict__ idx_list,
    ushort* __restrict__ KCh, ushort* __restrict__ KCl,
    ushort* __restrict__ VCth, ushort* __restrict__ VCtl) {
  int bh = blockIdx.x;        // 0..23
  int kc = blockIdx.y;        // 0..7
  int h = bh % H;
  __shared__ float vt[64][65];
  int tid = threadIdx.x;
  int kk = tid >> 2;           // key within chunk (0..63)
  int dq = (tid & 3) * 16;     // dh base (0,16,32,48)
  int j = kc*64 + kk;
  int srow = idx_list[h*TOPK + j];
  const float* kr = Kmat + ((size_t)bh*S + srow)*DH + dq;
  const float* vr = Vmat + ((size_t)bh*S + srow)*DH + dq;
  ushort hh[16], ll[16];
#pragma unroll
  for (int i = 0; i < 16; ++i) bf16_split(kr[i], hh[i], ll[i]);
  size_t kbase = ((size_t)bh*TOPK + j)*DH + dq;
  *(u16x8*)(KCh + kbase)     = *(u16x8*)&hh[0];
  *(u16x8*)(KCh + kbase + 8) = *(u16x8*)&hh[8];
  *(u16x8*)(KCl + kbase)     = *(u16x8*)&ll[0];
  *(u16x8*)(KCl + kbase + 8) = *(u16x8*)&ll[8];
#pragma unroll
  for (int i = 0; i < 16; ++i) vt[kk][dq + i] = vr[i];
  __syncthreads();
  int d  = tid >> 2;           // dh row (0..63)
  int kq = (tid & 3) * 16;     // key base within chunk
#pragma unroll
  for (int i = 0; i < 16; ++i) bf16_split(vt[kq + i][d], hh[i], ll[i]);
  size_t vbase = ((size_t)bh*DH + d)*TOPK + kc*64 + kq;
  *(u16x8*)(VCth + vbase)     = *(u16x8*)&hh[0];
  *(u16x8*)(VCth + vbase + 8) = *(u16x8*)&hh[8];
  *(u16x8*)(VCtl + vbase)     = *(u16x8*)&ll[0];
  *(u16x8*)(VCtl + vbase + 8) = *(u16x8*)&ll[8];
}

// ---------------------------------------------------------------------------
// MFMA attention, split-bf16: single pass, 4 waves/block, wave-private LDS.
// Epilogue writes CTX as bf16 hi/lo (feeds the MFMA output projection).
// ---------------------------------------------------------------------------
__global__ __launch_bounds__(256) void attn_kernel(
    const float* __restrict__ Q,
    const ushort* __restrict__ KCh, const ushort* __restrict__ KCl,
    const ushort* __restrict__ VCth, const ushort* __restrict__ VCtl,
    ushort* __restrict__ CTXh, ushort* __restrict__ CTXl) {
  __shared__ __align__(16) ushort SQh[4][16][88];
  __shared__ __align__(16) ushort SQl[4][16][88];
  int tid = threadIdx.x;
  int w = tid >> 6;
  int lane = tid & 63;
  int lr = lane & 15, lg = lane >> 4;
  int bh = blockIdx.x >> 5;
  int qt = blockIdx.x & 31;
  int qbase = qt*64 + w*16;
  int b = bh / H, h = bh % H;

  bf16x8 qh[2], ql[2];
#pragma unroll
  for (int ks = 0; ks < 2; ++ks) {
    const float* qp = Q + ((size_t)bh*S + qbase + lr)*DH + ks*32 + lg*8;
    float qv[8];
    *(float4*)&qv[0] = *(const float4*)qp;
    *(float4*)&qv[4] = *(const float4*)(qp + 4);
#pragma unroll
    for (int i = 0; i < 8; ++i) {
      ushort hh, lo; bf16_split(qv[i], hh, lo);
      qh[ks][i] = (short)hh; ql[ks][i] = (short)lo;
    }
  }

  f32x4 pacc[4] = {};
  float z_acc[4] = {};

  for (int c = 0; c < 8; ++c) {
    int keybase = c*64;
    f32x4 sacc[4] = {};
#pragma unroll
    for (int ks = 0; ks < 2; ++ks) {
#pragma unroll
      for (int f = 0; f < 4; ++f) {
        size_t koff = ((size_t)bh*TOPK + keybase + 16*f + lr)*DH + ks*32 + lg*8;
        bf16x8 kh = *(const bf16x8*)(KCh + koff);
        bf16x8 kl = *(const bf16x8*)(KCl + koff);
        sacc[f] = __builtin_amdgcn_mfma_f32_16x16x32_bf16(qh[ks], kh, sacc[f], 0, 0, 0);
        sacc[f] = __builtin_amdgcn_mfma_f32_16x16x32_bf16(qh[ks], kl, sacc[f], 0, 0, 0);
        sacc[f] = __builtin_amdgcn_mfma_f32_16x16x32_bf16(ql[ks], kh, sacc[f], 0, 0, 0);
      }
    }
    float zc[4] = {};
#pragma unroll
    for (int f = 0; f < 4; ++f) {
#pragma unroll
      for (int r = 0; r < 4; ++r) {
        float s = sacc[f][r];
        float sq = s*s;
        zc[r] += sq;
        ushort hh, lo; bf16_split(sq, hh, lo);
        SQh[w][lg*4 + r][16*f + lr] = hh;
        SQl[w][lg*4 + r][16*f + lr] = lo;
      }
    }
#pragma unroll
    for (int r = 0; r < 4; ++r) {
      float t = zc[r];
      t += __shfl_xor(t, 1);
      t += __shfl_xor(t, 2);
      t += __shfl_xor(t, 4);
      t += __shfl_xor(t, 8);
      z_acc[r] += t;
    }
#pragma unroll
    for (int ks = 0; ks < 2; ++ks) {
      bf16x8 ah = *(const bf16x8*)&SQh[w][lr][ks*32 + lg*8];
      bf16x8 al = *(const bf16x8*)&SQl[w][lr][ks*32 + lg*8];
#pragma unroll
      for (int f = 0; f < 4; ++f) {
        size_t voff = ((size_t)bh*DH + 16*f + lr)*TOPK + keybase + ks*32 + lg*8;
        bf16x8 vh = *(const bf16x8*)(VCth + voff);
        bf16x8 vl = *(const bf16x8*)(VCtl + voff);
        pacc[f] = __builtin_amdgcn_mfma_f32_16x16x32_bf16(ah, vh, pacc[f], 0, 0, 0);
        pacc[f] = __builtin_amdgcn_mfma_f32_16x16x32_bf16(ah, vl, pacc[f], 0, 0, 0);
        pacc[f] = __builtin_amdgcn_mfma_f32_16x16x32_bf16(al, vh, pacc[f], 0, 0, 0);
      }
    }
  }

  float zi[4];
#pragma unroll
  for (int r = 0; r < 4; ++r) zi[r] = 1.0f / (z_acc[r] + 1e-12f);
#pragma unroll
  for (int f = 0; f < 4; ++f) {
#pragma unroll
    for (int r = 0; r < 4; ++r) {
      int q = lg*4 + r;
      float val = pacc[f][r] * zi[r];
      ushort hh, lo; bf16_split(val, hh, lo);
      size_t o = ((size_t)b*S + qbase + q)*D + h*DH + 16*f + lr;
      CTXh[o] = hh; CTXl[o] = lo;
    }
  }
}

// ---------------------------------------------------------------------------
extern "C" void kernel_launch(void* const* d_in, const int* in_sizes, int n_in,
                              void* d_out, int out_size, void* d_ws, size_t ws_size,
                              hipStream_t stream) {
  const float* query = (const float*)d_in[0];
  const float* key   = (const float*)d_in[1];
  const float* value = (const float*)d_in[2];
  const float* Wq = (const float*)d_in[3];
  const float* bq = (const float*)d_in[4];
  const float* Wk = (const float*)d_in[5];
  const float* bk = (const float*)d_in[6];
  const float* Wv = (const float*)d_in[7];
  const float* bv = (const float*)d_in[8];
  const float* Wo = (const float*)d_in[9];
  const float* bo = (const float*)d_in[10];
  float* out = (float*)d_out;

  float* ws = (float*)d_ws;
  const size_t QKV = (size_t)B*H*S*DH;        // 3,145,728
  const size_t WSZ = (size_t)D*D;             // 589,824
  float* Qws   = ws;
  float* Kws   = Qws + QKV;
  float* Vws   = Kws + QKV;
  float* partials = Vws + QKV;                // 786,432
  float* invWs = partials + (size_t)H*16*4096;
  float* levWs = invWs + (size_t)H*4096;
  ushort* Xh  = (ushort*)(levWs + (size_t)H*S);   // input split / later CTX
  ushort* Xl  = Xh + QKV;
  ushort* Wqh = Xl + QKV;  ushort* Wql = Wqh + WSZ;
  ushort* Wkh = Wql + WSZ; ushort* Wkl = Wkh + WSZ;
  ushort* Wvh = Wkl + WSZ; ushort* Wvl = Wvh + WSZ;
  ushort* Woh = Wvl + WSZ; ushort* Wol = Woh + WSZ;
  ushort* KCh  = Wol + WSZ;
  ushort* KCl  = KCh  + (size_t)B*H*TOPK*DH;
  ushort* VCth = KCl  + (size_t)B*H*TOPK*DH;
  ushort* VCtl = VCth + (size_t)B*H*TOPK*DH;
  int*   idxWs = (int*)(VCtl + (size_t)B*H*TOPK*DH);

  const int nW8 = (int)(WSZ/8), nX8 = (int)(QKV/8);
  split_kernel<<<nW8/256, 256, 0, stream>>>(Wq, Wqh, Wql, nW8);
  split_kernel<<<nW8/256, 256, 0, stream>>>(Wk, Wkh, Wkl, nW8);
  split_kernel<<<nW8/256, 256, 0, stream>>>(Wv, Wvh, Wvl, nW8);
  split_kernel<<<nW8/256, 256, 0, stream>>>(Wo, Woh, Wol, nW8);

  dim3 pgrid(NROW/64, D/64);
  split_kernel<<<nX8/256, 256, 0, stream>>>(query, Xh, Xl, nX8);
  projmf_kernel<1><<<pgrid, 256, 0, stream>>>(Xh, Xl, Wqh, Wql, bq, Qws, 0.125f);
  split_kernel<<<nX8/256, 256, 0, stream>>>(key, Xh, Xl, nX8);
  projmf_kernel<1><<<pgrid, 256, 0, stream>>>(Xh, Xl, Wkh, Wkl, bk, Kws, 1.0f);
  split_kernel<<<nX8/256, 256, 0, stream>>>(value, Xh, Xl, nX8);
  projmf_kernel<1><<<pgrid, 256, 0, stream>>>(Xh, Xl, Wvh, Wvl, bv, Vws, 1.0f);

  levA1_kernel<<<dim3(H,16), 256, 0, stream>>>(Kws, partials);
  levA2_kernel<<<H, 64, 0, stream>>>(partials, invWs);
  levB_kernel<<<dim3(H,8), 256, 0, stream>>>(Kws, invWs, levWs);
  topk_kernel<<<H, 256, 0, stream>>>(levWs, idxWs);

  gather_kernel<<<dim3(B*H, TOPK/64), 256, 0, stream>>>(
      Kws, Vws, idxWs, KCh, KCl, VCth, VCtl);

  // attn writes CTX split into Xh/Xl (input splits are dead by now)
  attn_kernel<<<B*H*(S/64), 256, 0, stream>>>(Qws, KCh, KCl, VCth, VCtl, Xh, Xl);

  projmf_kernel<0><<<pgrid, 256, 0, stream>>>(Xh, Xl, Woh, Wol, bo, out, 1.0f);
}

// Round 5
// 633.839 us; speedup vs baseline: 1.3896x; 1.3142x over previous
//
#include <hip/hip_runtime.h>

#define B 2
#define S 2048
#define D 768
#define H 12
#define DH 64
#define TOPK 512
#define NROW (B*S)   // 4096

typedef __attribute__((ext_vector_type(8))) short bf16x8;
typedef __attribute__((ext_vector_type(8))) ushort u16x8;
typedef __attribute__((ext_vector_type(4))) float f32x4;

// ---- bf16 split helpers (hi = RNE bf16 of x, lo = RNE bf16 of residual) ----
__device__ __forceinline__ ushort bf16_hi(float x) {
  union { float f; unsigned u; } v; v.f = x;
  unsigned r = v.u + 0x7fffu + ((v.u >> 16) & 1u);
  return (ushort)(r >> 16);
}
__device__ __forceinline__ float bf16_tof(ushort h) {
  union { float f; unsigned u; } v; v.u = ((unsigned)h) << 16; return v.f;
}
__device__ __forceinline__ void bf16_split(float x, ushort& h, ushort& l) {
  h = bf16_hi(x);
  l = bf16_hi(x - bf16_tof(h));
}

// ---------------------------------------------------------------------------
// Split fp32 tensor -> bf16 hi/lo buffers. 8 elements/thread.
// ---------------------------------------------------------------------------
__global__ __launch_bounds__(256) void split_kernel(
    const float* __restrict__ src, ushort* __restrict__ dh,
    ushort* __restrict__ dl, int n8) {
  int i = blockIdx.x*256 + threadIdx.x;
  if (i >= n8) return;
  float v[8];
  *(float4*)&v[0] = ((const float4*)src)[i*2];
  *(float4*)&v[4] = ((const float4*)src)[i*2+1];
  ushort hh[8], ll[8];
#pragma unroll
  for (int k = 0; k < 8; ++k) bf16_split(v[k], hh[k], ll[k]);
  ((u16x8*)dh)[i] = *(u16x8*)&hh[0];
  ((u16x8*)dl)[i] = *(u16x8*)&ll[0];
}

// ---------------------------------------------------------------------------
// Split-bf16 MFMA GEMM: C = A (N x 768) @ W^T + bias, * scale
// Block 256 = 4 waves, tile 64x64, wave tile 32x32 (2x2 fragments).
// MODE 0: C row-major [N][768] fp32; MODE 1: C scattered to [b][h][s][dh]
// ---------------------------------------------------------------------------
template<int MODE>
__global__ __launch_bounds__(256) void projmf_kernel(
    const ushort* __restrict__ Ah, const ushort* __restrict__ Al,
    const ushort* __restrict__ Wh, const ushort* __restrict__ Wl,
    const float* __restrict__ bias, float* __restrict__ C, float scale) {
  int tid = threadIdx.x;
  int w = tid >> 6, lane = tid & 63;
  int lr = lane & 15, lg = lane >> 4;
  int n0 = blockIdx.x*64 + (w >> 1)*32;
  int m0 = blockIdx.y*64 + (w & 1)*32;
  f32x4 acc[2][2] = {};
  for (int ks = 0; ks < 24; ++ks) {
    int ko = ks*32 + lg*8;
    bf16x8 ah[2], al[2], wh[2], wl[2];
#pragma unroll
    for (int i = 0; i < 2; ++i) {
      size_t ao = (size_t)(n0 + 16*i + lr)*768 + ko;
      ah[i] = *(const bf16x8*)(Ah + ao);
      al[i] = *(const bf16x8*)(Al + ao);
      size_t wo = (size_t)(m0 + 16*i + lr)*768 + ko;
      wh[i] = *(const bf16x8*)(Wh + wo);
      wl[i] = *(const bf16x8*)(Wl + wo);
    }
#pragma unroll
    for (int i = 0; i < 2; ++i)
#pragma unroll
      for (int j = 0; j < 2; ++j) {
        acc[i][j] = __builtin_amdgcn_mfma_f32_16x16x32_bf16(ah[i], wh[j], acc[i][j], 0, 0, 0);
        acc[i][j] = __builtin_amdgcn_mfma_f32_16x16x32_bf16(ah[i], wl[j], acc[i][j], 0, 0, 0);
        acc[i][j] = __builtin_amdgcn_mfma_f32_16x16x32_bf16(al[i], wh[j], acc[i][j], 0, 0, 0);
        acc[i][j] = __builtin_amdgcn_mfma_f32_16x16x32_bf16(al[i], wl[j], acc[i][j], 0, 0, 0);
      }
  }
#pragma unroll
  for (int i = 0; i < 2; ++i)
#pragma unroll
    for (int j = 0; j < 2; ++j) {
      int m = m0 + 16*j + lr;
      float bv = bias[m];
#pragma unroll
      for (int r = 0; r < 4; ++r) {
        int n = n0 + 16*i + lg*4 + r;
        float val = (acc[i][j][r] + bv) * scale;
        if (MODE == 0) {
          C[(size_t)n*D + m] = val;
        } else {
          int b = n >> 11, s = n & 2047, hh = m >> 6, dh = m & 63;
          C[(((size_t)b*H + hh)*S + s)*DH + dh] = val;
        }
      }
    }
}

// ---------------------------------------------------------------------------
// Leverage stage A1: per-head partial KtK over 128-row chunks (batch 0 only)
// ---------------------------------------------------------------------------
__global__ __launch_bounds__(256) void levA1_kernel(
    const float* __restrict__ Kmat, float* __restrict__ partials) {
  int h = blockIdx.x, blk = blockIdx.y;
  __shared__ __align__(16) float ktile[128*64];
  int tid = threadIdx.x;
  const float* Kh = Kmat + ((size_t)h*S + (size_t)blk*128)*DH;
#pragma unroll
  for (int r = 0; r < 32; ++r) { int e = tid + 256*r; ktile[e] = Kh[e]; }
  __syncthreads();
  int j4 = tid & 15;
  float accf[4][4] = {};
  for (int ss = 0; ss < 128; ++ss) {
    float4 kj = ((const float4*)(ktile + ss*64))[j4];
#pragma unroll
    for (int r = 0; r < 4; ++r) {
      int i = (tid >> 4) + 16*r;
      float ki = ktile[ss*64 + i];
      accf[r][0] += ki*kj.x; accf[r][1] += ki*kj.y;
      accf[r][2] += ki*kj.z; accf[r][3] += ki*kj.w;
    }
  }
  size_t base = ((size_t)h*16 + blk)*4096;
#pragma unroll
  for (int r = 0; r < 4; ++r) {
    int i = (tid >> 4) + 16*r;
#pragma unroll
    for (int c = 0; c < 4; ++c)
      partials[base + (size_t)i*64 + j4*4 + c] = accf[r][c];
  }
}

// ---------------------------------------------------------------------------
// Leverage stage A0-reduce: wide parallel fp64 sum of the 16 partials
// (same p=0..15 order as before -> bitwise-identical KtK) + damping.
// ---------------------------------------------------------------------------
__global__ __launch_bounds__(256) void levA0_kernel(
    const float* __restrict__ partials, float* __restrict__ KtK) {
  int g = blockIdx.x*256 + threadIdx.x;        // 0 .. H*4096-1
  int h = g >> 12, e = g & 4095;
  const float* pb = partials + (size_t)h*65536 + e;
  double t = 0.0;
#pragma unroll
  for (int p = 0; p < 16; ++p) t += (double)pb[(size_t)p*4096];
  if ((e >> 6) == (e & 63)) t += 1e-6;
  KtK[g] = (float)t;
}

// ---------------------------------------------------------------------------
// Leverage stage A2: Gauss-Jordan inverse, one block (256 thr) per head.
// aug = [A | I] in LDS, stride 131 (odd -> 2-lane/bank, conflict-free).
// Thread (r = tid&63, quarter q = tid>>6) owns cols [q*32, q*32+32).
// Per pivot: phase-1 read f/piv, barrier, phase-2 redundant-normalize +
// fma update (EXACT same per-element arithmetic as R2/R4 -> same inverse
// bitwise), barrier. Row-p writes are safe: each quarter's columns are
// touched only by its own wave (lockstep read-before-write).
// ---------------------------------------------------------------------------
__global__ __launch_bounds__(256) void levA2_kernel(
    const float* __restrict__ KtK, float* __restrict__ invOut) {
  __shared__ float A_[64*131 + 1];
  int h = blockIdx.x, tid = threadIdx.x;
  int r = tid & 63, q = tid >> 6;
  int c0 = q * 32;
  // init: cols 0..63 = KtK (damped), cols 64..127 = I
  float* row = A_ + r*131;
  const float* src = KtK + (size_t)h*4096 + r*64;
#pragma unroll
  for (int i = 0; i < 32; ++i) {
    int c = c0 + i;
    row[c] = (c < 64) ? src[c] : ((c - 64 == r) ? 1.0f : 0.0f);
  }
  __syncthreads();
  for (int p = 0; p < 64; ++p) {
    float f = row[p];                  // own row's old col-p value
    float piv = A_[p*131 + p];
    float ipiv = 1.0f / piv;
    bool isp = (r == p);
    __syncthreads();                   // reads done before col p rewritten
    const float* prow = A_ + p*131;
#pragma unroll
    for (int i = 0; i < 32; ++i) {
      int c = c0 + i;
      float n = prow[c] * ipiv;        // normalized row p (redundant)
      row[c] = isp ? n : fmaf(-f, n, row[c]);
    }
    __syncthreads();
  }
  // extract inverse (cols 64..127)
  size_t obase = (size_t)h*4096 + (size_t)tid*16;
#pragma unroll
  for (int i = 0; i < 16; ++i) {
    int e = tid*16 + i;
    invOut[obase + i] = A_[(e >> 6)*131 + 64 + (e & 63)];
  }
}

// ---------------------------------------------------------------------------
// Leverage stage B: lev[h][s] = k_s^T inv_h k_s
// ---------------------------------------------------------------------------
__global__ __launch_bounds__(256) void levB_kernel(
    const float* __restrict__ Kmat, const float* __restrict__ invMat,
    float* __restrict__ lev) {
  int h = blockIdx.x;
  int s = blockIdx.y*256 + threadIdx.x;
  __shared__ __align__(16) float inv[64*64];
#pragma unroll
  for (int r = 0; r < 16; ++r)
    inv[threadIdx.x + 256*r] = invMat[(size_t)h*4096 + threadIdx.x + 256*r];
  __syncthreads();
  float kv[64];
  const float* kr = Kmat + ((size_t)h*S + s)*DH;
#pragma unroll
  for (int d4 = 0; d4 < 16; ++d4) {
    float4 t = ((const float4*)kr)[d4];
    kv[4*d4+0]=t.x; kv[4*d4+1]=t.y; kv[4*d4+2]=t.z; kv[4*d4+3]=t.w;
  }
  float acc = 0.f;
  for (int i = 0; i < 64; ++i) {
    float ti = 0.f;
    const float4* ir = (const float4*)(inv + i*64);
#pragma unroll
    for (int j4 = 0; j4 < 16; ++j4) {
      float4 iv = ir[j4];
      ti += iv.x*kv[4*j4] + iv.y*kv[4*j4+1] + iv.z*kv[4*j4+2] + iv.w*kv[4*j4+3];
    }
    acc += ti * kv[i];
  }
  lev[(size_t)h*S + s] = acc;
}

// ---------------------------------------------------------------------------
// Top-k via bitonic sort (value desc, index asc)
// ---------------------------------------------------------------------------
__global__ __launch_bounds__(256) void topk_kernel(
    const float* __restrict__ lev, int* __restrict__ idx_list) {
  int h = blockIdx.x, tid = threadIdx.x;
  __shared__ float sv[2048];
  __shared__ int   si[2048];
#pragma unroll
  for (int r = 0; r < 8; ++r) {
    int e = tid + 256*r;
    sv[e] = lev[(size_t)h*S + e];
    si[e] = e;
  }
  __syncthreads();
  for (int k = 2; k <= 2048; k <<= 1) {
    for (int j = k >> 1; j > 0; j >>= 1) {
      for (int r = 0; r < 8; ++r) {
        int i = tid + 256*r;
        int l = i ^ j;
        if (l > i) {
          float v1 = sv[i], v2 = sv[l];
          int   i1 = si[i], i2 = si[l];
          bool before = (v1 > v2) || (v1 == v2 && i1 < i2);
          bool dir = ((i & k) == 0);
          if (before != dir) { sv[i]=v2; sv[l]=v1; si[i]=i2; si[l]=i1; }
        }
      }
      __syncthreads();
    }
  }
#pragma unroll
  for (int r = 0; r < 2; ++r) {
    int t = tid + 256*r;
    idx_list[h*TOPK + t] = si[t];
  }
}

// ---------------------------------------------------------------------------
// Gather kept K/V rows -> bf16 split buffers.
// KCh/KCl: [bh][512][64]; VCth/VCtl: [bh][64][512] (transposed)
// ---------------------------------------------------------------------------
__global__ __launch_bounds__(256) void gather_kernel(
    const float* __restrict__ Kmat, const float* __restrict__ Vmat,
    const int* __restrict__ idx_list,
    ushort* __restrict__ KCh, ushort* __restrict__ KCl,
    ushort* __restrict__ VCth, ushort* __restrict__ VCtl) {
  int bh = blockIdx.x;        // 0..23
  int kc = blockIdx.y;        // 0..7
  int h = bh % H;
  __shared__ float vt[64][65];
  int tid = threadIdx.x;
  int kk = tid >> 2;           // key within chunk (0..63)
  int dq = (tid & 3) * 16;     // dh base (0,16,32,48)
  int j = kc*64 + kk;
  int srow = idx_list[h*TOPK + j];
  const float* kr = Kmat + ((size_t)bh*S + srow)*DH + dq;
  const float* vr = Vmat + ((size_t)bh*S + srow)*DH + dq;
  ushort hh[16], ll[16];
#pragma unroll
  for (int i = 0; i < 16; ++i) bf16_split(kr[i], hh[i], ll[i]);
  size_t kbase = ((size_t)bh*TOPK + j)*DH + dq;
  *(u16x8*)(KCh + kbase)     = *(u16x8*)&hh[0];
  *(u16x8*)(KCh + kbase + 8) = *(u16x8*)&hh[8];
  *(u16x8*)(KCl + kbase)     = *(u16x8*)&ll[0];
  *(u16x8*)(KCl + kbase + 8) = *(u16x8*)&ll[8];
#pragma unroll
  for (int i = 0; i < 16; ++i) vt[kk][dq + i] = vr[i];
  __syncthreads();
  int d  = tid >> 2;           // dh row (0..63)
  int kq = (tid & 3) * 16;     // key base within chunk
#pragma unroll
  for (int i = 0; i < 16; ++i) bf16_split(vt[kq + i][d], hh[i], ll[i]);
  size_t vbase = ((size_t)bh*DH + d)*TOPK + kc*64 + kq;
  *(u16x8*)(VCth + vbase)     = *(u16x8*)&hh[0];
  *(u16x8*)(VCth + vbase + 8) = *(u16x8*)&hh[8];
  *(u16x8*)(VCtl + vbase)     = *(u16x8*)&ll[0];
  *(u16x8*)(VCtl + vbase + 8) = *(u16x8*)&ll[8];
}

// ---------------------------------------------------------------------------
// MFMA attention, split-bf16: single pass, 4 waves/block, wave-private LDS.
// Epilogue writes CTX as bf16 hi/lo (feeds the MFMA output projection).
// ---------------------------------------------------------------------------
__global__ __launch_bounds__(256) void attn_kernel(
    const float* __restrict__ Q,
    const ushort* __restrict__ KCh, const ushort* __restrict__ KCl,
    const ushort* __restrict__ VCth, const ushort* __restrict__ VCtl,
    ushort* __restrict__ CTXh, ushort* __restrict__ CTXl) {
  __shared__ __align__(16) ushort SQh[4][16][88];
  __shared__ __align__(16) ushort SQl[4][16][88];
  int tid = threadIdx.x;
  int w = tid >> 6;
  int lane = tid & 63;
  int lr = lane & 15, lg = lane >> 4;
  int bh = blockIdx.x >> 5;
  int qt = blockIdx.x & 31;
  int qbase = qt*64 + w*16;
  int b = bh / H, h = bh % H;

  bf16x8 qh[2], ql[2];
#pragma unroll
  for (int ks = 0; ks < 2; ++ks) {
    const float* qp = Q + ((size_t)bh*S + qbase + lr)*DH + ks*32 + lg*8;
    float qv[8];
    *(float4*)&qv[0] = *(const float4*)qp;
    *(float4*)&qv[4] = *(const float4*)(qp + 4);
#pragma unroll
    for (int i = 0; i < 8; ++i) {
      ushort hh, lo; bf16_split(qv[i], hh, lo);
      qh[ks][i] = (short)hh; ql[ks][i] = (short)lo;
    }
  }

  f32x4 pacc[4] = {};
  float z_acc[4] = {};

  for (int c = 0; c < 8; ++c) {
    int keybase = c*64;
    f32x4 sacc[4] = {};
#pragma unroll
    for (int ks = 0; ks < 2; ++ks) {
#pragma unroll
      for (int f = 0; f < 4; ++f) {
        size_t koff = ((size_t)bh*TOPK + keybase + 16*f + lr)*DH + ks*32 + lg*8;
        bf16x8 kh = *(const bf16x8*)(KCh + koff);
        bf16x8 kl = *(const bf16x8*)(KCl + koff);
        sacc[f] = __builtin_amdgcn_mfma_f32_16x16x32_bf16(qh[ks], kh, sacc[f], 0, 0, 0);
        sacc[f] = __builtin_amdgcn_mfma_f32_16x16x32_bf16(qh[ks], kl, sacc[f], 0, 0, 0);
        sacc[f] = __builtin_amdgcn_mfma_f32_16x16x32_bf16(ql[ks], kh, sacc[f], 0, 0, 0);
      }
    }
    float zc[4] = {};
#pragma unroll
    for (int f = 0; f < 4; ++f) {
#pragma unroll
      for (int r = 0; r < 4; ++r) {
        float s = sacc[f][r];
        float sq = s*s;
        zc[r] += sq;
        ushort hh, lo; bf16_split(sq, hh, lo);
        SQh[w][lg*4 + r][16*f + lr] = hh;
        SQl[w][lg*4 + r][16*f + lr] = lo;
      }
    }
#pragma unroll
    for (int r = 0; r < 4; ++r) {
      float t = zc[r];
      t += __shfl_xor(t, 1);
      t += __shfl_xor(t, 2);
      t += __shfl_xor(t, 4);
      t += __shfl_xor(t, 8);
      z_acc[r] += t;
    }
#pragma unroll
    for (int ks = 0; ks < 2; ++ks) {
      bf16x8 ah = *(const bf16x8*)&SQh[w][lr][ks*32 + lg*8];
      bf16x8 al = *(const bf16x8*)&SQl[w][lr][ks*32 + lg*8];
#pragma unroll
      for (int f = 0; f < 4; ++f) {
        size_t voff = ((size_t)bh*DH + 16*f + lr)*TOPK + keybase + ks*32 + lg*8;
        bf16x8 vh = *(const bf16x8*)(VCth + voff);
        bf16x8 vl = *(const bf16x8*)(VCtl + voff);
        pacc[f] = __builtin_amdgcn_mfma_f32_16x16x32_bf16(ah, vh, pacc[f], 0, 0, 0);
        pacc[f] = __builtin_amdgcn_mfma_f32_16x16x32_bf16(ah, vl, pacc[f], 0, 0, 0);
        pacc[f] = __builtin_amdgcn_mfma_f32_16x16x32_bf16(al, vh, pacc[f], 0, 0, 0);
      }
    }
  }

  float zi[4];
#pragma unroll
  for (int r = 0; r < 4; ++r) zi[r] = 1.0f / (z_acc[r] + 1e-12f);
#pragma unroll
  for (int f = 0; f < 4; ++f) {
#pragma unroll
    for (int r = 0; r < 4; ++r) {
      int q = lg*4 + r;
      float val = pacc[f][r] * zi[r];
      ushort hh, lo; bf16_split(val, hh, lo);
      size_t o = ((size_t)b*S + qbase + q)*D + h*DH + 16*f + lr;
      CTXh[o] = hh; CTXl[o] = lo;
    }
  }
}

// ---------------------------------------------------------------------------
extern "C" void kernel_launch(void* const* d_in, const int* in_sizes, int n_in,
                              void* d_out, int out_size, void* d_ws, size_t ws_size,
                              hipStream_t stream) {
  const float* query = (const float*)d_in[0];
  const float* key   = (const float*)d_in[1];
  const float* value = (const float*)d_in[2];
  const float* Wq = (const float*)d_in[3];
  const float* bq = (const float*)d_in[4];
  const float* Wk = (const float*)d_in[5];
  const float* bk = (const float*)d_in[6];
  const float* Wv = (const float*)d_in[7];
  const float* bv = (const float*)d_in[8];
  const float* Wo = (const float*)d_in[9];
  const float* bo = (const float*)d_in[10];
  float* out = (float*)d_out;

  float* ws = (float*)d_ws;
  const size_t QKV = (size_t)B*H*S*DH;        // 3,145,728
  const size_t WSZ = (size_t)D*D;             // 589,824
  float* Qws   = ws;
  float* Kws   = Qws + QKV;
  float* Vws   = Kws + QKV;
  float* partials = Vws + QKV;                // 786,432
  float* ktkWs = partials + (size_t)H*16*4096;// H*4096
  float* invWs = ktkWs + (size_t)H*4096;      // H*4096
  float* levWs = invWs + (size_t)H*4096;
  ushort* Xh  = (ushort*)(levWs + (size_t)H*S);   // input split / later CTX
  ushort* Xl  = Xh + QKV;
  ushort* Wqh = Xl + QKV;  ushort* Wql = Wqh + WSZ;
  ushort* Wkh = Wql + WSZ; ushort* Wkl = Wkh + WSZ;
  ushort* Wvh = Wkl + WSZ; ushort* Wvl = Wvh + WSZ;
  ushort* Woh = Wvl + WSZ; ushort* Wol = Woh + WSZ;
  ushort* KCh  = Wol + WSZ;
  ushort* KCl  = KCh  + (size_t)B*H*TOPK*DH;
  ushort* VCth = KCl  + (size_t)B*H*TOPK*DH;
  ushort* VCtl = VCth + (size_t)B*H*TOPK*DH;
  int*   idxWs = (int*)(VCtl + (size_t)B*H*TOPK*DH);

  const int nW8 = (int)(WSZ/8), nX8 = (int)(QKV/8);
  split_kernel<<<nW8/256, 256, 0, stream>>>(Wq, Wqh, Wql, nW8);
  split_kernel<<<nW8/256, 256, 0, stream>>>(Wk, Wkh, Wkl, nW8);
  split_kernel<<<nW8/256, 256, 0, stream>>>(Wv, Wvh, Wvl, nW8);
  split_kernel<<<nW8/256, 256, 0, stream>>>(Wo, Woh, Wol, nW8);

  dim3 pgrid(NROW/64, D/64);
  split_kernel<<<nX8/256, 256, 0, stream>>>(query, Xh, Xl, nX8);
  projmf_kernel<1><<<pgrid, 256, 0, stream>>>(Xh, Xl, Wqh, Wql, bq, Qws, 0.125f);
  split_kernel<<<nX8/256, 256, 0, stream>>>(key, Xh, Xl, nX8);
  projmf_kernel<1><<<pgrid, 256, 0, stream>>>(Xh, Xl, Wkh, Wkl, bk, Kws, 1.0f);
  split_kernel<<<nX8/256, 256, 0, stream>>>(value, Xh, Xl, nX8);
  projmf_kernel<1><<<pgrid, 256, 0, stream>>>(Xh, Xl, Wvh, Wvl, bv, Vws, 1.0f);

  levA1_kernel<<<dim3(H,16), 256, 0, stream>>>(Kws, partials);
  levA0_kernel<<<(H*4096)/256, 256, 0, stream>>>(partials, ktkWs);
  levA2_kernel<<<H, 256, 0, stream>>>(ktkWs, invWs);
  levB_kernel<<<dim3(H,8), 256, 0, stream>>>(Kws, invWs, levWs);
  topk_kernel<<<H, 256, 0, stream>>>(levWs, idxWs);

  gather_kernel<<<dim3(B*H, TOPK/64), 256, 0, stream>>>(
      Kws, Vws, idxWs, KCh, KCl, VCth, VCtl);

  // attn writes CTX split into Xh/Xl (input splits are dead by now)
  attn_kernel<<<B*H*(S/64), 256, 0, stream>>>(Qws, KCh, KCl, VCth, VCtl, Xh, Xl);

  projmf_kernel<0><<<pgrid, 256, 0, stream>>>(Xh, Xl, Woh, Wol, bo, out, 1.0f);
}